// Round 1
// baseline (855.994 us; speedup 1.0000x reference)
//
#include <hip/hip_runtime.h>

// CRF forward (logZ) + Viterbi (best score + backpointers), fused.
// S=1024, B=1024, T=32.  One wave per batch; lane = (g, i): i = tag (0..31),
// g = j-half (each lane sums 16 of the 32 j terms, combined via shfl_xor 32).
// State alpha/scores replicated across the two halves.
// Forward uses E = exp(trans) factorization -> inner loop is pure FMA.
// Viterbi value path is bit-exact vs numpy; argmax is strict-first-max.

#define SS 1024
#define BB 1024
#define TT 32
#define POFF (2 * BB)   // pointers output offset in d_out (after logZ, best_score)

__global__ __launch_bounds__(64) void crf_fused_kernel(
    const float* __restrict__ feats,
    const float* __restrict__ mask,
    const float* __restrict__ trans,
    float* __restrict__ out) {

  const int b    = blockIdx.x;
  const int lane = threadIdx.x;
  const int g    = lane >> 5;   // j-half: 0 -> j 0..15, 1 -> j 16..31
  const int i    = lane & 31;   // tag index
  const int j0   = g << 4;

  __shared__ __align__(16) float p_row[TT];
  __shared__ __align__(16) float sc_row[TT];

  // Per-lane constants: trans[i][j0..j0+15] and E = exp(trans) for forward.
  float tr[16], er[16];
#pragma unroll
  for (int k = 0; k < 16; ++k) {
    float t = trans[i * TT + j0 + k];
    tr[k] = t;
    er[k] = __expf(t);   // exp(-10000) underflows to exactly 0 -> correct
  }
  const float t_stop = trans[30 * TT + i];   // trans[STOP_TAG][i]

  float alpha = (i == 29) ? 0.0f : -10000.0f;   // START_TAG = 29
  float sc    = alpha;
  float M     = 0.0f;   // max_j alpha_j (exact at init; refreshed each step)

  // ---- viterbi argmax over j (first-max semantics, replicated result) ----
  auto vit_step = [&](float& best, int& ptr) {
    sc_row[i] = sc;                      // both halves write same value
    __builtin_amdgcn_wave_barrier();
    float4 s0 = *(const float4*)&sc_row[j0];
    float4 s1 = *(const float4*)&sc_row[j0 + 4];
    float4 s2 = *(const float4*)&sc_row[j0 + 8];
    float4 s3 = *(const float4*)&sc_row[j0 + 12];
    float cs[16] = {s0.x, s0.y, s0.z, s0.w, s1.x, s1.y, s1.z, s1.w,
                    s2.x, s2.y, s2.z, s2.w, s3.x, s3.y, s3.z, s3.w};
    // two independent sub-chains (shorter dependency chains), merge prefers A
    float bA = cs[0] + tr[0]; int pA = j0;
#pragma unroll
    for (int k = 1; k < 8; ++k) {
      float c = cs[k] + tr[k];
      bool t = c > bA; bA = t ? c : bA; pA = t ? (j0 + k) : pA;
    }
    float bB = cs[8] + tr[8]; int pB = j0 + 8;
#pragma unroll
    for (int k = 9; k < 16; ++k) {
      float c = cs[k] + tr[k];
      bool t = c > bB; bB = t ? c : bB; pB = t ? (j0 + k) : pB;
    }
    { bool t = bB > bA; bA = t ? bB : bA; pA = t ? pB : pA; }
    // cross-half combine; low half wins ties (first-max over full 0..31)
    float ob = __shfl_xor(bA, 32, 64);
    int   op = __shfl_xor(pA, 32, 64);
    float lowB  = g ? ob : bA;  int lowP  = g ? op : pA;
    float highB = g ? bA : ob;  int highP = g ? pA : op;
    bool t = highB > lowB;
    best = t ? highB : lowB;
    ptr  = t ? highP : lowP;
  };

  // ---- forward step: alpha_i = f_i + M + log(sum_j E_ij * exp(alpha_j - M))
  auto fwd_step = [&](float f_i) {
    float p = __expf(alpha - M);
    p_row[i] = p;
    __builtin_amdgcn_wave_barrier();
    float4 p0 = *(const float4*)&p_row[j0];
    float4 p1 = *(const float4*)&p_row[j0 + 4];
    float4 p2 = *(const float4*)&p_row[j0 + 8];
    float4 p3 = *(const float4*)&p_row[j0 + 12];
    float a0 = er[0] * p0.x; float a1 = er[1] * p0.y;
    float a2 = er[2] * p0.z; float a3 = er[3] * p0.w;
    a0 = fmaf(er[4],  p1.x, a0); a1 = fmaf(er[5],  p1.y, a1);
    a2 = fmaf(er[6],  p1.z, a2); a3 = fmaf(er[7],  p1.w, a3);
    a0 = fmaf(er[8],  p2.x, a0); a1 = fmaf(er[9],  p2.y, a1);
    a2 = fmaf(er[10], p2.z, a2); a3 = fmaf(er[11], p2.w, a3);
    a0 = fmaf(er[12], p3.x, a0); a1 = fmaf(er[13], p3.y, a1);
    a2 = fmaf(er[14], p3.z, a2); a3 = fmaf(er[15], p3.w, a3);
    float aa = (a0 + a1) + (a2 + a3);
    float D = aa + __shfl_xor(aa, 32, 64);   // combine the two j-halves
    alpha = M + f_i + __logf(D);             // log(0) = -inf is correct here
    // refresh M for next step; off the critical path (consumed next iter)
    float Mn = alpha;
#pragma unroll
    for (int d = 1; d < 32; d <<= 1) Mn = fmaxf(Mn, __shfl_xor(Mn, d, 64));
    M = Mn;
  };

  int s_exit = SS;

  // software pipeline: feats/mask prefetched 4 steps ahead (hide ~900cyc HBM)
  float f[4], mk[4];
#pragma unroll
  for (int u = 0; u < 4; ++u) {
    f[u]  = feats[(u * BB + b) * TT + i];
    mk[u] = mask[u * BB + b];
  }

#pragma unroll 1
  for (int s = 0; s < SS; s += 4) {
    float nf[4], nm[4];
#pragma unroll
    for (int u = 0; u < 4; ++u) {
      int su = (s + 4 + u < SS) ? (s + 4 + u) : 0;   // clamped harmless prefetch
      nf[u] = feats[(su * BB + b) * TT + i];
      nm[u] = mask[su * BB + b];
    }
#pragma unroll
    for (int u = 0; u < 4; ++u) {
      if (mk[u] == 0.0f) { s_exit = s + u; goto tail; }  // mask is monotone
      fwd_step(f[u]);
      float best; int ptr;
      vit_step(best, ptr);
      if (g == 0) out[POFF + ((s + u) * BB + b) * TT + i] = (float)ptr;
      sc = best + f[u];
    }
#pragma unroll
    for (int u = 0; u < 4; ++u) { f[u] = nf[u]; mk[u] = nm[u]; }
  }

tail:
  // scores frozen for masked steps -> pointer row is constant: compute once,
  // then store-only loop (both halves store alternating steps).
  {
    float tb; int tp;
    vit_step(tb, tp);
    float tv = (float)tp;
    for (int s2 = s_exit + g; s2 < SS; s2 += 2)
      out[POFF + (s2 * BB + b) * TT + i] = tv;
  }

  // epilogue: logZ = LSE_i(alpha_i + trans[STOP][i]); best = max_i(sc + ...)
  {
    float v = alpha + t_stop;
    float M2 = v;
#pragma unroll
    for (int d = 1; d < 32; d <<= 1) M2 = fmaxf(M2, __shfl_xor(M2, d, 64));
    float e = __expf(v - M2);
#pragma unroll
    for (int d = 1; d < 32; d <<= 1) e += __shfl_xor(e, d, 64);
    float logZ = M2 + __logf(e);

    float w = sc + t_stop;
    float bsc = w;
#pragma unroll
    for (int d = 1; d < 32; d <<= 1) bsc = fmaxf(bsc, __shfl_xor(bsc, d, 64));

    if (lane == 0) {
      out[b]      = logZ;
      out[BB + b] = bsc;
    }
  }
}

extern "C" void kernel_launch(void* const* d_in, const int* in_sizes, int n_in,
                              void* d_out, int out_size, void* d_ws, size_t ws_size,
                              hipStream_t stream) {
  const float* feats = (const float*)d_in[0];
  const float* msk   = (const float*)d_in[1];
  const float* trans = (const float*)d_in[2];
  float* out = (float*)d_out;
  (void)in_sizes; (void)n_in; (void)out_size; (void)d_ws; (void)ws_size;
  crf_fused_kernel<<<dim3(BB), dim3(64), 0, stream>>>(feats, msk, trans, out);
}

// Round 2
// 582.913 us; speedup vs baseline: 1.4685x; 1.4685x over previous
//
#include <hip/hip_runtime.h>

// CRF forward (logZ) + Viterbi (best score + backpointers), SPLIT into two
// independent waves per batch (grid = [B, 2]): role 0 = forward, role 1 =
// viterbi. 2048 waves total -> 2 waves/SIMD so the two ~280-cyc dependency
// chains interleave on each SIMD.
//
// Forward: E = exp(trans) factorization -> pure-FMA matvec; the shift M is
// readfirstlane(alpha) (alpha[0] is always finite and within ~25 of max; M
// only needs to be within +-80 of max) -> no 5-shfl reduce on the chain.
// Viterbi: value path bit-exact vs numpy; argmax = depth-4 tree with strict
// '>' preferring lower index (np.argmax first-max semantics).

#define SS 1024
#define BB 1024
#define TT 32
#define POFF (2 * BB)   // pointers offset in d_out (after logZ, best_score)

__global__ __launch_bounds__(64) void crf_split_kernel(
    const float* __restrict__ feats,
    const float* __restrict__ mask,
    const float* __restrict__ trans,
    float* __restrict__ out) {

  const int b    = blockIdx.x;
  const int lane = threadIdx.x;
  const int g    = lane >> 5;   // j-half: 0 -> j 0..15, 1 -> j 16..31
  const int i    = lane & 31;   // tag index
  const int j0   = g << 4;

  __shared__ __align__(16) float row[TT];

  const float t_stop = trans[30 * TT + i];   // trans[STOP_TAG][i]

  // 4-deep feats/mask software pipeline (hide ~900cyc HBM latency)
  float f[4], mk[4];
#pragma unroll
  for (int u = 0; u < 4; ++u) {
    f[u]  = feats[(u * BB + b) * TT + i];
    mk[u] = mask[u * BB + b];
  }

  if (blockIdx.y == 0) {
    // ================= forward (logZ) wave =================
    float er[16];
#pragma unroll
    for (int k = 0; k < 16; ++k)
      er[k] = __expf(trans[i * TT + j0 + k]);   // exp(-10000) == 0 exactly

    float alpha = (i == 29) ? 0.0f : -10000.0f;   // START_TAG = 29
    float M = 0.0f;   // exact max at init (alpha_29 = 0)

#pragma unroll 1
    for (int s = 0; s < SS; s += 4) {
      float nf[4], nm[4];
#pragma unroll
      for (int u = 0; u < 4; ++u) {
        int su = (s + 4 + u < SS) ? (s + 4 + u) : 0;  // clamped prefetch
        nf[u] = feats[(su * BB + b) * TT + i];
        nm[u] = mask[su * BB + b];
      }
#pragma unroll
      for (int u = 0; u < 4; ++u) {
        if (mk[u] == 0.0f) goto fwd_done;   // mask is monotone
        float p = __expf(alpha - M);
        row[i] = p;                          // both halves: same value
        __builtin_amdgcn_wave_barrier();
        float4 p0 = *(const float4*)&row[j0];
        float4 p1 = *(const float4*)&row[j0 + 4];
        float4 p2 = *(const float4*)&row[j0 + 8];
        float4 p3 = *(const float4*)&row[j0 + 12];
        __builtin_amdgcn_wave_barrier();
        float a0 = er[0] * p0.x, a1 = er[1] * p0.y;
        float a2 = er[2] * p0.z, a3 = er[3] * p0.w;
        a0 = fmaf(er[4],  p1.x, a0); a1 = fmaf(er[5],  p1.y, a1);
        a2 = fmaf(er[6],  p1.z, a2); a3 = fmaf(er[7],  p1.w, a3);
        a0 = fmaf(er[8],  p2.x, a0); a1 = fmaf(er[9],  p2.y, a1);
        a2 = fmaf(er[10], p2.z, a2); a3 = fmaf(er[11], p2.w, a3);
        a0 = fmaf(er[12], p3.x, a0); a1 = fmaf(er[13], p3.y, a1);
        a2 = fmaf(er[14], p3.z, a2); a3 = fmaf(er[15], p3.w, a3);
        float aa = (a0 + a1) + (a2 + a3);
        float D = aa + __shfl_xor(aa, 32, 64);   // combine j-halves
        alpha = M + f[u] + __logf(D);            // log(0) = -inf is correct
        // cheap shift for next step: alpha[0] (always finite, near pack max)
        M = __uint_as_float(
              __builtin_amdgcn_readfirstlane(__float_as_uint(alpha)));
      }
#pragma unroll
      for (int u = 0; u < 4; ++u) { f[u] = nf[u]; mk[u] = nm[u]; }
    }
fwd_done:
    {
      // logZ = LSE_i(alpha_i + trans[STOP][i]) with exact max (once, cheap)
      float v = alpha + t_stop;
      float M2 = v;
#pragma unroll
      for (int d = 1; d < 32; d <<= 1) M2 = fmaxf(M2, __shfl_xor(M2, d, 64));
      float e = __expf(v - M2);
#pragma unroll
      for (int d = 1; d < 32; d <<= 1) e += __shfl_xor(e, d, 64);
      if (lane == 0) out[b] = M2 + __logf(e);
    }
    return;
  }

  // ================= viterbi wave =================
  {
    float tr[16];
#pragma unroll
    for (int k = 0; k < 16; ++k)
      tr[k] = trans[i * TT + j0 + k];

    float sc = (i == 29) ? 0.0f : -10000.0f;
    int s_exit = SS;

    // argmax over j, first-max semantics, replicated across halves
    auto vit_step = [&](float& best, int& ptr) {
      row[i] = sc;
      __builtin_amdgcn_wave_barrier();
      float4 s0 = *(const float4*)&row[j0];
      float4 s1 = *(const float4*)&row[j0 + 4];
      float4 s2 = *(const float4*)&row[j0 + 8];
      float4 s3 = *(const float4*)&row[j0 + 12];
      __builtin_amdgcn_wave_barrier();
      float v[16] = {s0.x, s0.y, s0.z, s0.w, s1.x, s1.y, s1.z, s1.w,
                     s2.x, s2.y, s2.z, s2.w, s3.x, s3.y, s3.z, s3.w};
      int ix[16];
#pragma unroll
      for (int k = 0; k < 16; ++k) { v[k] += tr[k]; ix[k] = j0 + k; }
      // depth-4 tree; strict '>' so lower index wins ties (np.argmax)
#pragma unroll
      for (int st = 1; st < 16; st <<= 1) {
#pragma unroll
        for (int k = 0; k < 16; k += 2 * st) {
          bool t = v[k + st] > v[k];
          v[k]  = t ? v[k + st] : v[k];
          ix[k] = t ? ix[k + st] : ix[k];
        }
      }
      // cross-half merge; low half (lower j) wins ties
      float ob = __shfl_xor(v[0], 32, 64);
      int   op = __shfl_xor(ix[0], 32, 64);
      float lowB  = g ? ob : v[0];   int lowP  = g ? op : ix[0];
      float highB = g ? v[0] : ob;   int highP = g ? ix[0] : op;
      bool t = highB > lowB;
      best = t ? highB : lowB;
      ptr  = t ? highP : lowP;
    };

#pragma unroll 1
    for (int s = 0; s < SS; s += 4) {
      float nf[4], nm[4];
#pragma unroll
      for (int u = 0; u < 4; ++u) {
        int su = (s + 4 + u < SS) ? (s + 4 + u) : 0;
        nf[u] = feats[(su * BB + b) * TT + i];
        nm[u] = mask[su * BB + b];
      }
#pragma unroll
      for (int u = 0; u < 4; ++u) {
        if (mk[u] == 0.0f) { s_exit = s + u; goto vit_tail; }
        float best; int ptr;
        vit_step(best, ptr);
        if (g == 0) out[POFF + ((s + u) * BB + b) * TT + i] = (float)ptr;
        sc = best + f[u];   // identical float ops as numpy -> bit-exact
      }
#pragma unroll
      for (int u = 0; u < 4; ++u) { f[u] = nf[u]; mk[u] = nm[u]; }
    }
vit_tail:
    {
      // frozen scores -> constant ptr row: compute once, store-only loop
      float tb; int tp;
      vit_step(tb, tp);
      float tv = (float)tp;
      for (int s2 = s_exit + g; s2 < SS; s2 += 2)
        out[POFF + (s2 * BB + b) * TT + i] = tv;

      float w = sc + t_stop;
#pragma unroll
      for (int d = 1; d < 32; d <<= 1) w = fmaxf(w, __shfl_xor(w, d, 64));
      if (lane == 0) out[BB + b] = w;
    }
  }
}

extern "C" void kernel_launch(void* const* d_in, const int* in_sizes, int n_in,
                              void* d_out, int out_size, void* d_ws, size_t ws_size,
                              hipStream_t stream) {
  const float* feats = (const float*)d_in[0];
  const float* msk   = (const float*)d_in[1];
  const float* trans = (const float*)d_in[2];
  float* out = (float*)d_out;
  (void)in_sizes; (void)n_in; (void)out_size; (void)d_ws; (void)ws_size;
  crf_split_kernel<<<dim3(BB, 2), dim3(64), 0, stream>>>(feats, msk, trans, out);
}

// Round 3
// 577.180 us; speedup vs baseline: 1.4831x; 1.0099x over previous
//
#include <hip/hip_runtime.h>

// CRF forward (logZ) + Viterbi (best score + backpointers).
// Grid (B/2, 2): role 0 = forward, role 1 = viterbi. Each wave handles TWO
// batches (lanes 0..31 = batch b0, lanes 32..63 = batch b0+1); each lane owns
// one tag cell and sums all 32 j-terms in-register -> NO cross-lane ops in
// the step loop (the j-half shfl_xor combine of round 2 is gone).
// 1024 waves = 1/SIMD: wall == dependency chain, no wave phase-serialization.
//
// Forward: E = exp(trans) -> pure-FMA matvec. Shift M tracks alpha[0] via
// M += clamp(log p[0], -20, .) -- p[0] already read for the FMA, so the
// shift needs no cross-lane traffic and stays uniform per batch.
// Viterbi: value path bit-exact vs numpy; argmax = strict-'>' leftmost tree
// (np.argmax first-max), int indices (inline constants).

#define SS 1024
#define BB 1024
#define TT 32
#define POFF (2 * BB)   // pointers offset in d_out (after logZ, best_score)

__global__ __launch_bounds__(64) void crf2_kernel(
    const float* __restrict__ feats,
    const float* __restrict__ mask,
    const float* __restrict__ trans,
    float* __restrict__ out) {

  const int l  = threadIdx.x;
  const int h  = l >> 5;        // which batch of the pair
  const int i  = l & 31;        // tag
  const int b0 = blockIdx.x * 2;
  const int b  = b0 + h;

  __shared__ __align__(16) float row[64];

  const float* fbase = feats + (size_t)b0 * TT + l;   // + s*BB*TT per step
  const float* mbase = mask + b;                      // + s*BB per step
  const float t_stop = trans[30 * TT + i];            // trans[STOP_TAG][i]

  // 8-deep feats/mask prefetch (two 4-buffers)
  float f0[4], m0[4], f1[4], m1[4];
#pragma unroll
  for (int u = 0; u < 4; ++u) {
    f0[u] = fbase[(size_t)u * BB * TT];
    m0[u] = mbase[(size_t)u * BB];
    f1[u] = fbase[(size_t)(u + 4) * BB * TT];
    m1[u] = mbase[(size_t)(u + 4) * BB];
  }

  if (blockIdx.y == 0) {
    // ======================= forward (logZ) =======================
    float er[32];
#pragma unroll
    for (int k = 0; k < 32; ++k)
      er[k] = __expf(trans[i * TT + k]);   // exp(-10000) == 0 exactly

    float alpha = (i == 29) ? 0.0f : -10000.0f;   // START_TAG = 29
    float M = 0.0f;

#pragma unroll 1
    for (int s = 0; s < SS; s += 4) {
      float nf[4], nm[4];
#pragma unroll
      for (int u = 0; u < 4; ++u) {
        int su = (s + 8 + u < SS) ? (s + 8 + u) : 0;   // clamped prefetch
        nf[u] = fbase[(size_t)su * BB * TT];
        nm[u] = mbase[(size_t)su * BB];
      }
#pragma unroll
      for (int u = 0; u < 4; ++u) {
        bool act = (m0[u] != 0.0f);
        if (__ballot(act) == 0ull) goto fwd_done;   // both batches done
        float p = __expf(alpha - M);
        row[l] = p;
        __builtin_amdgcn_wave_barrier();
        const float4* q = (const float4*)&row[h * 32];
        float4 q0 = q[0], q1 = q[1], q2 = q[2], q3 = q[3];
        float4 q4 = q[4], q5 = q[5], q6 = q[6], q7 = q[7];
        __builtin_amdgcn_wave_barrier();
        float a0 = er[0] * q0.x, a1 = er[1] * q0.y;
        float a2 = er[2] * q0.z, a3 = er[3] * q0.w;
        a0 = fmaf(er[4],  q1.x, a0); a1 = fmaf(er[5],  q1.y, a1);
        a2 = fmaf(er[6],  q1.z, a2); a3 = fmaf(er[7],  q1.w, a3);
        a0 = fmaf(er[8],  q2.x, a0); a1 = fmaf(er[9],  q2.y, a1);
        a2 = fmaf(er[10], q2.z, a2); a3 = fmaf(er[11], q2.w, a3);
        a0 = fmaf(er[12], q3.x, a0); a1 = fmaf(er[13], q3.y, a1);
        a2 = fmaf(er[14], q3.z, a2); a3 = fmaf(er[15], q3.w, a3);
        a0 = fmaf(er[16], q4.x, a0); a1 = fmaf(er[17], q4.y, a1);
        a2 = fmaf(er[18], q4.z, a2); a3 = fmaf(er[19], q4.w, a3);
        a0 = fmaf(er[20], q5.x, a0); a1 = fmaf(er[21], q5.y, a1);
        a2 = fmaf(er[22], q5.z, a2); a3 = fmaf(er[23], q5.w, a3);
        a0 = fmaf(er[24], q6.x, a0); a1 = fmaf(er[25], q6.y, a1);
        a2 = fmaf(er[26], q6.z, a2); a3 = fmaf(er[27], q6.w, a3);
        a0 = fmaf(er[28], q7.x, a0); a1 = fmaf(er[29], q7.y, a1);
        a2 = fmaf(er[30], q7.z, a2); a3 = fmaf(er[31], q7.w, a3);
        float D = (a0 + a1) + (a2 + a3);
        float nv = M + f0[u] + __logf(D);   // log(0) = -inf is correct
        alpha = act ? nv : alpha;
        // shift update: M -> alpha[0] (2 steps stale). p[0] is q0.x.
        // clamp -20 handles the step-1 underflow (p[0]==0 -> log=-inf).
        M = M + fmaxf(__logf(q0.x), -20.0f);
      }
#pragma unroll
      for (int u = 0; u < 4; ++u) {
        f0[u] = f1[u]; m0[u] = m1[u]; f1[u] = nf[u]; m1[u] = nm[u];
      }
    }
fwd_done:
    {
      // logZ = LSE over own 32 lanes of (alpha + trans[STOP][i])
      float v = alpha + t_stop;
      float M2 = v;
#pragma unroll
      for (int d = 1; d < 32; d <<= 1) M2 = fmaxf(M2, __shfl_xor(M2, d, 64));
      float e = __expf(v - M2);
#pragma unroll
      for (int d = 1; d < 32; d <<= 1) e += __shfl_xor(e, d, 64);
      if (i == 0) out[b] = M2 + __logf(e);
    }
    return;
  }

  // ========================= viterbi =========================
  {
    float tr[32];
#pragma unroll
    for (int k = 0; k < 32; ++k) tr[k] = trans[i * TT + k];

    float sc = (i == 29) ? 0.0f : -10000.0f;
    int s_exit = SS;

    // argmax over 32 j in-register; strict '>' leftmost-max (np.argmax)
    auto vstep = [&](float& best, int& ptr) {
      row[l] = sc;
      __builtin_amdgcn_wave_barrier();
      const float4* q = (const float4*)&row[h * 32];
      float4 q0 = q[0], q1 = q[1], q2 = q[2], q3 = q[3];
      float4 q4 = q[4], q5 = q[5], q6 = q[6], q7 = q[7];
      __builtin_amdgcn_wave_barrier();
      float v[32];
      v[0]  = q0.x + tr[0];  v[1]  = q0.y + tr[1];
      v[2]  = q0.z + tr[2];  v[3]  = q0.w + tr[3];
      v[4]  = q1.x + tr[4];  v[5]  = q1.y + tr[5];
      v[6]  = q1.z + tr[6];  v[7]  = q1.w + tr[7];
      v[8]  = q2.x + tr[8];  v[9]  = q2.y + tr[9];
      v[10] = q2.z + tr[10]; v[11] = q2.w + tr[11];
      v[12] = q3.x + tr[12]; v[13] = q3.y + tr[13];
      v[14] = q3.z + tr[14]; v[15] = q3.w + tr[15];
      v[16] = q4.x + tr[16]; v[17] = q4.y + tr[17];
      v[18] = q4.z + tr[18]; v[19] = q4.w + tr[19];
      v[20] = q5.x + tr[20]; v[21] = q5.y + tr[21];
      v[22] = q5.z + tr[22]; v[23] = q5.w + tr[23];
      v[24] = q6.x + tr[24]; v[25] = q6.y + tr[25];
      v[26] = q6.z + tr[26]; v[27] = q6.w + tr[27];
      v[28] = q7.x + tr[28]; v[29] = q7.y + tr[29];
      v[30] = q7.z + tr[30]; v[31] = q7.w + tr[31];
      int ix[32];
#pragma unroll
      for (int k = 0; k < 32; ++k) ix[k] = k;   // inline int constants
#pragma unroll
      for (int st = 1; st < 32; st <<= 1) {
#pragma unroll
        for (int k = 0; k < 32; k += 2 * st) {
          bool t = v[k + st] > v[k];
          v[k]  = t ? v[k + st] : v[k];
          ix[k] = t ? ix[k + st] : ix[k];
        }
      }
      best = v[0];
      ptr  = ix[0];
    };

#pragma unroll 1
    for (int s = 0; s < SS; s += 4) {
      float nf[4], nm[4];
#pragma unroll
      for (int u = 0; u < 4; ++u) {
        int su = (s + 8 + u < SS) ? (s + 8 + u) : 0;
        nf[u] = fbase[(size_t)su * BB * TT];
        nm[u] = mbase[(size_t)su * BB];
      }
#pragma unroll
      for (int u = 0; u < 4; ++u) {
        bool act = (m0[u] != 0.0f);
        if (__ballot(act) == 0ull) { s_exit = s + u; goto vit_tail; }
        float best; int ptr;
        vstep(best, ptr);
        out[POFF + (size_t)(s + u) * BB * TT + b0 * TT + l] = (float)ptr;
        sc = act ? best + f0[u] : sc;   // same float ops as numpy: bit-exact
      }
#pragma unroll
      for (int u = 0; u < 4; ++u) {
        f0[u] = f1[u]; m0[u] = m1[u]; f1[u] = nf[u]; m1[u] = nm[u];
      }
    }
vit_tail:
    {
      // scores frozen -> pointer rows constant: compute once, store-only
      float tb; int tp;
      vstep(tb, tp);
      float tj = (float)tp;
      for (int s2 = s_exit; s2 < SS; ++s2)
        out[POFF + (size_t)s2 * BB * TT + b0 * TT + l] = tj;

      float w = sc + t_stop;
#pragma unroll
      for (int d = 1; d < 32; d <<= 1) w = fmaxf(w, __shfl_xor(w, d, 64));
      if (i == 0) out[BB + b] = w;
    }
  }
}

extern "C" void kernel_launch(void* const* d_in, const int* in_sizes, int n_in,
                              void* d_out, int out_size, void* d_ws, size_t ws_size,
                              hipStream_t stream) {
  const float* feats = (const float*)d_in[0];
  const float* msk   = (const float*)d_in[1];
  const float* trans = (const float*)d_in[2];
  float* out = (float*)d_out;
  (void)in_sizes; (void)n_in; (void)out_size; (void)d_ws; (void)ws_size;
  crf2_kernel<<<dim3(BB / 2, 2), dim3(64), 0, stream>>>(feats, msk, trans, out);
}

// Round 4
// 545.810 us; speedup vs baseline: 1.5683x; 1.0575x over previous
//
#include <hip/hip_runtime.h>

// CRF forward (logZ) + Viterbi (best score + backpointers).
// Grid (B/2, 2): blockIdx.y = role (0 fwd, 1 vit). One wave per block; each
// wave covers TWO batches (lanes 0..31 = b0, 32..63 = b0+1), lane = tag.
// 1024 waves = 1/SIMD; wall == per-step dependency chain, so this round is
// about CHAIN LENGTH:
//   fwd propagates p = exp(alpha - C) directly:
//     p_new[i] = exp(f_i) * (sum_j E_ij p_j) * (1/q0c),  C += log(q0c)
//   where q0c = clamped p_0 from the LDS read-back (uniform per batch).
//   exp(f) is load-dependent only, log feeds only C (consumed in epilogue):
//   NO transcendental on the recurrence. Update is degree-0 homogeneous in p
//   -> scale cannot drift; clamp(1e-20) + C bookkeeping is an exact identity.
// Viterbi value path bit-exact vs numpy (same float adds/maxes, strict '>'
// leftmost-max tree == np.argmax first-max semantics).

#define SS 1024
#define BB 1024
#define TT 32
#define POFF (2 * BB)   // pointers offset in d_out (after logZ, best_score)

static __device__ __forceinline__ float fastrcp(float x) {
#if __has_builtin(__builtin_amdgcn_rcpf)
  return __builtin_amdgcn_rcpf(x);
#else
  return 1.0f / x;
#endif
}

__global__ __launch_bounds__(64, 1) void crf3_kernel(
    const float* __restrict__ feats,
    const float* __restrict__ mask,
    const float* __restrict__ trans,
    float* __restrict__ out) {

  const int l  = threadIdx.x;
  const int h  = l >> 5;        // which batch of the pair
  const int i  = l & 31;        // tag
  const int b0 = blockIdx.x * 2;
  const int b  = b0 + h;

  __shared__ __align__(16) float row[64];

  const float* fbase = feats + (size_t)b0 * TT + l;   // + s*BB*TT per step
  const float* mbase = mask + b;                      // + s*BB per step
  const float t_stop = trans[30 * TT + i];            // trans[STOP_TAG][i]

  // 8-step prefetch in two 4-buffers; refills placed right after consumption
  // (no rotation copies).
  float fA[4], mA[4], fB[4], mB[4];
#pragma unroll
  for (int u = 0; u < 4; ++u) {
    fA[u] = fbase[(size_t)u * (BB * TT)];
    mA[u] = mbase[(size_t)u * BB];
    fB[u] = fbase[(size_t)(u + 4) * (BB * TT)];
    mB[u] = mbase[(size_t)(u + 4) * BB];
  }

  if (blockIdx.y == 0) {
    // ======================= forward (logZ) =======================
    float er[32];
#pragma unroll
    for (int k = 0; k < 32; ++k)
      er[k] = __expf(trans[i * TT + k]);   // exp(-10000) == 0 exactly

    float p = (i == 29) ? 1.0f : 0.0f;     // exp(alpha0), START_TAG = 29
    float C = 0.0f;

    auto fstep = [&](float fv, float mv) {
      bool act = (mv != 0.0f);
      float ef = __expf(fv);               // off-chain: depends on load only
      row[l] = p;
      __builtin_amdgcn_wave_barrier();
      const float4* q = (const float4*)&row[h * 32];
      float4 q0 = q[0], q1 = q[1], q2 = q[2], q3 = q[3];
      float4 q4 = q[4], q5 = q[5], q6 = q[6], q7 = q[7];
      __builtin_amdgcn_wave_barrier();
      float q0c = fmaxf(q0.x, 1e-20f);     // uniform per batch-half
      float r = fastrcp(q0c);              // parallel to the FMA tree
      float a0 = er[0] * q0.x, a1 = er[1] * q0.y;
      float a2 = er[2] * q0.z, a3 = er[3] * q0.w;
      a0 = fmaf(er[4],  q1.x, a0); a1 = fmaf(er[5],  q1.y, a1);
      a2 = fmaf(er[6],  q1.z, a2); a3 = fmaf(er[7],  q1.w, a3);
      a0 = fmaf(er[8],  q2.x, a0); a1 = fmaf(er[9],  q2.y, a1);
      a2 = fmaf(er[10], q2.z, a2); a3 = fmaf(er[11], q2.w, a3);
      a0 = fmaf(er[12], q3.x, a0); a1 = fmaf(er[13], q3.y, a1);
      a2 = fmaf(er[14], q3.z, a2); a3 = fmaf(er[15], q3.w, a3);
      a0 = fmaf(er[16], q4.x, a0); a1 = fmaf(er[17], q4.y, a1);
      a2 = fmaf(er[18], q4.z, a2); a3 = fmaf(er[19], q4.w, a3);
      a0 = fmaf(er[20], q5.x, a0); a1 = fmaf(er[21], q5.y, a1);
      a2 = fmaf(er[22], q5.z, a2); a3 = fmaf(er[23], q5.w, a3);
      a0 = fmaf(er[24], q6.x, a0); a1 = fmaf(er[25], q6.y, a1);
      a2 = fmaf(er[26], q6.z, a2); a3 = fmaf(er[27], q6.w, a3);
      a0 = fmaf(er[28], q7.x, a0); a1 = fmaf(er[29], q7.y, a1);
      a2 = fmaf(er[30], q7.z, a2); a3 = fmaf(er[31], q7.w, a3);
      float D = (a0 + a1) + (a2 + a3);
      float pn = D * r * ef;               // chain: RT + tree + 2 muls
      p = act ? pn : p;
      C += act ? __logf(q0c) : 0.0f;       // off-chain (epilogue-only)
    };

#pragma unroll 1
    for (int s = 0; s < SS; s += 8) {
      if (__ballot(mA[0] != 0.0f) == 0ull) goto fwd_done;  // monotone mask
#pragma unroll
      for (int u = 0; u < 4; ++u) fstep(fA[u], mA[u]);
#pragma unroll
      for (int u = 0; u < 4; ++u) {        // refill A with s+8..s+11
        int su = s + 8 + u; su = (su < SS) ? su : 0;
        fA[u] = fbase[(size_t)su * (BB * TT)];
        mA[u] = mbase[(size_t)su * BB];
      }
      if (__ballot(mB[0] != 0.0f) == 0ull) goto fwd_done;
#pragma unroll
      for (int u = 0; u < 4; ++u) fstep(fB[u], mB[u]);
#pragma unroll
      for (int u = 0; u < 4; ++u) {        // refill B with s+12..s+15
        int su = s + 12 + u; su = (su < SS) ? su : 0;
        fB[u] = fbase[(size_t)su * (BB * TT)];
        mB[u] = mbase[(size_t)su * BB];
      }
    }
fwd_done:
    {
      float alpha = C + __logf(p);         // p==0 -> -inf (dead tags), OK
      float v = alpha + t_stop;
      float M2 = v;
#pragma unroll
      for (int d = 1; d < 32; d <<= 1) M2 = fmaxf(M2, __shfl_xor(M2, d, 64));
      float e = __expf(v - M2);
#pragma unroll
      for (int d = 1; d < 32; d <<= 1) e += __shfl_xor(e, d, 64);
      if (i == 0) out[b] = M2 + __logf(e);
    }
    return;
  }

  // ========================= viterbi =========================
  {
    float tr[32];
#pragma unroll
    for (int k = 0; k < 32; ++k) tr[k] = trans[i * TT + k];

    float sc = (i == 29) ? 0.0f : -10000.0f;
    int s_exit = SS;

    auto vstep = [&](float& best, int& ptr) {
      row[l] = sc;
      __builtin_amdgcn_wave_barrier();
      const float4* q = (const float4*)&row[h * 32];
      float4 q0 = q[0], q1 = q[1], q2 = q[2], q3 = q[3];
      float4 q4 = q[4], q5 = q[5], q6 = q[6], q7 = q[7];
      __builtin_amdgcn_wave_barrier();
      float v[32];
      v[0]  = q0.x + tr[0];  v[1]  = q0.y + tr[1];
      v[2]  = q0.z + tr[2];  v[3]  = q0.w + tr[3];
      v[4]  = q1.x + tr[4];  v[5]  = q1.y + tr[5];
      v[6]  = q1.z + tr[6];  v[7]  = q1.w + tr[7];
      v[8]  = q2.x + tr[8];  v[9]  = q2.y + tr[9];
      v[10] = q2.z + tr[10]; v[11] = q2.w + tr[11];
      v[12] = q3.x + tr[12]; v[13] = q3.y + tr[13];
      v[14] = q3.z + tr[14]; v[15] = q3.w + tr[15];
      v[16] = q4.x + tr[16]; v[17] = q4.y + tr[17];
      v[18] = q4.z + tr[18]; v[19] = q4.w + tr[19];
      v[20] = q5.x + tr[20]; v[21] = q5.y + tr[21];
      v[22] = q5.z + tr[22]; v[23] = q5.w + tr[23];
      v[24] = q6.x + tr[24]; v[25] = q6.y + tr[25];
      v[26] = q6.z + tr[26]; v[27] = q6.w + tr[27];
      v[28] = q7.x + tr[28]; v[29] = q7.y + tr[29];
      v[30] = q7.z + tr[30]; v[31] = q7.w + tr[31];
      int ix[32];
#pragma unroll
      for (int k = 0; k < 32; ++k) ix[k] = k;
#pragma unroll
      for (int st = 1; st < 32; st <<= 1) {
#pragma unroll
        for (int k = 0; k < 32; k += 2 * st) {
          bool t = v[k + st] > v[k];       // strict: left wins ties
          v[k]  = t ? v[k + st] : v[k];
          ix[k] = t ? ix[k + st] : ix[k];
        }
      }
      best = v[0];
      ptr  = ix[0];
    };

#pragma unroll 1
    for (int s = 0; s < SS; s += 8) {
      if (__ballot(mA[0] != 0.0f) == 0ull) { s_exit = s; goto vtail; }
#pragma unroll
      for (int u = 0; u < 4; ++u) {
        float best; int ptr;
        vstep(best, ptr);
        out[POFF + (size_t)(s + u) * (BB * TT) + b0 * TT + l] = (float)ptr;
        sc = (mA[u] != 0.0f) ? (best + fA[u]) : sc;   // bit-exact vs numpy
      }
#pragma unroll
      for (int u = 0; u < 4; ++u) {
        int su = s + 8 + u; su = (su < SS) ? su : 0;
        fA[u] = fbase[(size_t)su * (BB * TT)];
        mA[u] = mbase[(size_t)su * BB];
      }
      if (__ballot(mB[0] != 0.0f) == 0ull) { s_exit = s + 4; goto vtail; }
#pragma unroll
      for (int u = 0; u < 4; ++u) {
        float best; int ptr;
        vstep(best, ptr);
        out[POFF + (size_t)(s + 4 + u) * (BB * TT) + b0 * TT + l] = (float)ptr;
        sc = (mB[u] != 0.0f) ? (best + fB[u]) : sc;
      }
#pragma unroll
      for (int u = 0; u < 4; ++u) {
        int su = s + 12 + u; su = (su < SS) ? su : 0;
        fB[u] = fbase[(size_t)su * (BB * TT)];
        mB[u] = mbase[(size_t)su * BB];
      }
    }
vtail:
    {
      // frozen scores -> constant ptr rows: compute once, store-only loop
      float tb; int tp;
      vstep(tb, tp);
      float tj = (float)tp;
      for (int s2 = s_exit; s2 < SS; ++s2)
        out[POFF + (size_t)s2 * (BB * TT) + b0 * TT + l] = tj;

      float w = sc + t_stop;
#pragma unroll
      for (int d = 1; d < 32; d <<= 1) w = fmaxf(w, __shfl_xor(w, d, 64));
      if (i == 0) out[BB + b] = w;
    }
  }
}

extern "C" void kernel_launch(void* const* d_in, const int* in_sizes, int n_in,
                              void* d_out, int out_size, void* d_ws, size_t ws_size,
                              hipStream_t stream) {
  const float* feats = (const float*)d_in[0];
  const float* msk   = (const float*)d_in[1];
  const float* trans = (const float*)d_in[2];
  float* out = (float*)d_out;
  (void)in_sizes; (void)n_in; (void)out_size; (void)d_ws; (void)ws_size;
  crf3_kernel<<<dim3(BB / 2, 2), dim3(64), 0, stream>>>(feats, msk, trans, out);
}